// Round 12
// baseline (456.357 us; speedup 1.0000x reference)
//
#include <hip/hip_runtime.h>
#include <hip/hip_fp16.h>
#include <math.h>

#define N_NODES 100000
#define N_EDGES 3200000
#define IN_CH   256
#define HID     64
#define OUTC    32
#define NB      ((N_NODES + 255) / 256)   // 391 scan blocks
#define NBUCK   ((N_NODES + 127) / 128)   // 782 buckets of 128 nodes (bucket = dst >> 7)
#define CHUNK   4096                      // edges per partition block
#define EPT     16                        // edges per thread (CHUNK/256)
#define CAP     4608                      // bucket capacity: mean 4092, sigma ~64 -> +8 sigma

// ---------------- workspace layout (bytes) ----------------
static constexpr size_t align256(size_t x) { return (x + 255) & ~(size_t)255; }
static constexpr size_t OFF_DEG  = 0;                                          // N ints
static constexpr size_t OFF_PTR  = OFF_DEG  + align256((size_t)N_NODES * 4);   // N ints (exclusive)
static constexpr size_t OFF_BSUM = OFF_PTR  + align256((size_t)N_NODES * 4);   // 512 ints
static constexpr size_t OFF_GCUR = OFF_BSUM + align256(512 * 4);               // NBUCK ints
static constexpr size_t OFF_DIS  = OFF_GCUR + align256((size_t)NBUCK * 4);     // N floats
static constexpr size_t OFF_SRC  = OFF_DIS  + align256((size_t)N_NODES * 4);   // E ints
static constexpr size_t OFF_PART = OFF_SRC  + align256((size_t)N_EDGES * 4);   // NBUCK*CAP ints (14.4 MB)
// s1h (N*64 halves = 12.8 MB) aliases PART (part dead after bucket_fill, before gemm1)
static constexpr size_t OFF_S1   = OFF_PART;
static constexpr size_t OFF_H1   = OFF_PART + align256((size_t)NBUCK * CAP * 4);  // N*64 floats (25.6 MB)
static constexpr size_t OFF_S2   = OFF_H1 + align256((size_t)N_NODES * HID * 4);  // N*32 halves (6.4 MB)
// total ~60 MB

// ---------------- bucket cursor init: gcur[b] = b*CAP ----------------
__global__ __launch_bounds__(256) void bucket_init(int* __restrict__ gcur) {
    int b = blockIdx.x * 256 + threadIdx.x;
    if (b < NBUCK) gcur[b] = b * CAP;
}

// ---------------- phase A: partition edges into dst-buckets (single pass) --------
__global__ __launch_bounds__(256) void partition_edges(const int* __restrict__ row,
                                                       const int* __restrict__ col,
                                                       int* __restrict__ gcur,
                                                       int* __restrict__ part) {
    __shared__ int lhist[NBUCK];
    __shared__ int lbase[NBUCK];
    const int t  = threadIdx.x;
    const int e0 = blockIdx.x * CHUNK;
    for (int i = t; i < NBUCK; i += 256) lhist[i] = 0;
    __syncthreads();

    int pk[EPT], br[EPT];
#pragma unroll
    for (int i = 0; i < EPT; ++i) {
        int e = e0 + i * 256 + t;
        if (e < N_EDGES) {
            int d = col[e];
            int b = d >> 7;
            int r = atomicAdd(&lhist[b], 1);
            pk[i] = row[e] | ((d & 127) << 17);
            br[i] = b | (r << 10);           // b<1024, r<4096 -> fits
        } else {
            br[i] = -1;
        }
    }
    __syncthreads();

    const int off = (int)((blockIdx.x * 131u) % NBUCK);
    for (int i = t; i < NBUCK; i += 256) {
        int bb = i + off;
        if (bb >= NBUCK) bb -= NBUCK;
        int c = lhist[bb];
        lbase[bb] = (c > 0) ? atomicAdd(&gcur[bb], c) : 0;
    }
    __syncthreads();

#pragma unroll
    for (int i = 0; i < EPT; ++i) {
        if (br[i] >= 0) {
            int b = br[i] & 1023;
            int r = br[i] >> 10;
            part[lbase[b] + r] = pk[i];
        }
    }
}

// ---------------- phase B1: per-node degree + dis from bucket data ---------------
__global__ __launch_bounds__(256) void bucket_hist(const int* __restrict__ gcur,
                                                   const int* __restrict__ part,
                                                   int* __restrict__ deg,
                                                   float* __restrict__ dis) {
    __shared__ int lh[128];
    const int b = blockIdx.x;
    const int t = threadIdx.x;
    if (t < 128) lh[t] = 0;
    __syncthreads();
    const int cnt = gcur[b] - b * CAP;
    for (int i = t; i < cnt; i += 256)
        atomicAdd(&lh[part[(size_t)b * CAP + i] >> 17], 1);
    __syncthreads();
    int v = b * 128 + t;
    if (t < 128 && v < N_NODES) {
        int d = lh[t];
        deg[v] = d;
        dis[v] = rsqrtf((float)d + 1.0f);   // +1 self-loop
    }
}

// ---------------- 3-kernel exclusive scan of deg -> ptr ----------------
__global__ __launch_bounds__(256) void scan_block_sums(const int* __restrict__ deg,
                                                       int* __restrict__ bsum) {
    __shared__ int buf[256];
    unsigned i = blockIdx.x * 256u + threadIdx.x;
    int v = (i < N_NODES) ? deg[i] : 0;
    buf[threadIdx.x] = v;
    __syncthreads();
    for (int off = 128; off > 0; off >>= 1) {
        if (threadIdx.x < (unsigned)off) buf[threadIdx.x] += buf[threadIdx.x + off];
        __syncthreads();
    }
    if (threadIdx.x == 0) bsum[blockIdx.x] = buf[0];
}

__global__ __launch_bounds__(512) void scan_bsum(int* __restrict__ bsum) {
    __shared__ int buf[512];
    int t = threadIdx.x;
    int v = (t < NB) ? bsum[t] : 0;
    buf[t] = v;
    __syncthreads();
    for (int off = 1; off < 512; off <<= 1) {
        int add = (t >= off) ? buf[t - off] : 0;
        __syncthreads();
        buf[t] += add;
        __syncthreads();
    }
    if (t < NB) bsum[t] = buf[t] - v;  // exclusive
}

__global__ __launch_bounds__(256) void scan_block_scan(const int* __restrict__ deg,
                                                       const int* __restrict__ bsum,
                                                       int* __restrict__ ptr) {
    __shared__ int buf[256];
    unsigned i = blockIdx.x * 256u + threadIdx.x;
    int v = (i < N_NODES) ? deg[i] : 0;
    buf[threadIdx.x] = v;
    __syncthreads();
    for (int off = 1; off < 256; off <<= 1) {
        int add = (threadIdx.x >= (unsigned)off) ? buf[threadIdx.x - off] : 0;
        __syncthreads();
        buf[threadIdx.x] += add;
        __syncthreads();
    }
    if (i < N_NODES) ptr[i] = bsum[blockIdx.x] + buf[threadIdx.x] - v;  // exclusive
}

// ---------------- phase B2: fill srcs; writes confined to ~16KB window/block -------
__global__ __launch_bounds__(256) void bucket_fill(const int* __restrict__ gcur,
                                                   const int* __restrict__ part,
                                                   const int* __restrict__ ptr,
                                                   int* __restrict__ srcs) {
    __shared__ int lcur[128];
    const int b = blockIdx.x;
    const int t = threadIdx.x;
    if (t < 128) lcur[t] = 0;
    __syncthreads();
    const int cnt = gcur[b] - b * CAP;
    for (int i = t; i < cnt; i += 256) {
        int p    = part[(size_t)b * CAP + i];
        int dlow = p >> 17;
        int src  = p & 0x1FFFF;
        int r    = atomicAdd(&lcur[dlow], 1);        // LDS cursor
        srcs[ptr[b * 128 + dlow] + r] = src;
    }
}

// ---------------- GEMM1: s1h[n][j] = fp16(dis[n] * (x[n,:] @ W1[:,j])) ----------
// r11 structure + SOFTWARE PIPELINE: chunk kt+1's VMEM loads are issued into
// registers BEFORE computing chunk kt; the vmcnt wait lands after 16 k4-steps
// of FMA (latency covered), at the regs->LDS write. 2 barriers/chunk remain
// but no VMEM round trip sits on the critical path.
__global__ __launch_bounds__(256) void gemm1(const float* __restrict__ x,
                                             const float* __restrict__ W1,
                                             const float* __restrict__ dis,
                                             __half* __restrict__ s1h) {
    __shared__ float wlds[64 * HID];   // 16 KB k-chunk of W1: [k_local][j]
    __shared__ float xlds[64 * 68];    // 17 KB x-tile: [row_local][k_local], stride 68

    const int t  = threadIdx.x;
    const int tx = t & 15;
    const int ty = t >> 4;
    const int row0 = blockIdx.x * 64;

    // staging geometry (constant across chunks)
    const int srl = t >> 2;                 // unused helper removed; keep L-based below
    (void)srl;

    float4 wreg[4], xreg[4];

    // ---- prefetch chunk 0
    {
        const float4* w4 = (const float4*)W1;
#pragma unroll
        for (int i = 0; i < 4; ++i) wreg[i] = w4[i * 256 + t];
#pragma unroll
        for (int i = 0; i < 4; ++i) {
            int L  = i * 256 + t;
            int rl = L >> 4;
            int k4 = L & 15;
            int rg = row0 + rl;
            xreg[i] = (rg < N_NODES) ? ((const float4*)x)[(size_t)rg * 64 + k4]
                                     : make_float4(0.f, 0.f, 0.f, 0.f);
        }
    }
    // ---- write chunk 0 to LDS
    {
        float4* l4 = (float4*)wlds;
#pragma unroll
        for (int i = 0; i < 4; ++i) l4[i * 256 + t] = wreg[i];
#pragma unroll
        for (int i = 0; i < 4; ++i) {
            int L  = i * 256 + t;
            int rl = L >> 4;
            int k4 = L & 15;
            *(float4*)(&xlds[rl * 68 + k4 * 4]) = xreg[i];
        }
    }
    __syncthreads();

    float acc[4][4] = {{0.f}};

#pragma unroll
    for (int kt = 0; kt < IN_CH / 64; ++kt) {
        // ---- prefetch chunk kt+1 into registers (VMEM issued, no wait)
        if (kt < IN_CH / 64 - 1) {
            const float4* w4 = (const float4*)(W1 + (size_t)(kt + 1) * 64 * HID);
#pragma unroll
            for (int i = 0; i < 4; ++i) wreg[i] = w4[i * 256 + t];
#pragma unroll
            for (int i = 0; i < 4; ++i) {
                int L  = i * 256 + t;
                int rl = L >> 4;
                int k4 = L & 15;
                int rg = row0 + rl;
                xreg[i] = (rg < N_NODES)
                              ? ((const float4*)x)[(size_t)rg * 64 + (kt + 1) * 16 + k4]
                              : make_float4(0.f, 0.f, 0.f, 0.f);
            }
        }

        // ---- compute on LDS chunk kt
        const float4* wl4 = (const float4*)wlds;
#pragma unroll 4
        for (int k4 = 0; k4 < 16; ++k4) {
            float4 xv[4];
#pragma unroll
            for (int i = 0; i < 4; ++i)
                xv[i] = *(const float4*)(&xlds[(ty * 4 + i) * 68 + k4 * 4]);
#pragma unroll
            for (int kk = 0; kk < 4; ++kk) {
                float4 bv = wl4[(k4 * 4 + kk) * 16 + tx];
#pragma unroll
                for (int i = 0; i < 4; ++i) {
                    const float* xf = (const float*)&xv[i];
                    float a = xf[kk];
                    acc[i][0] += a * bv.x;
                    acc[i][1] += a * bv.y;
                    acc[i][2] += a * bv.z;
                    acc[i][3] += a * bv.w;
                }
            }
        }

        // ---- rotate LDS buffers
        if (kt < IN_CH / 64 - 1) {
            __syncthreads();   // all waves done reading chunk kt
            float4* l4 = (float4*)wlds;
#pragma unroll
            for (int i = 0; i < 4; ++i) l4[i * 256 + t] = wreg[i];   // waits vmcnt here
#pragma unroll
            for (int i = 0; i < 4; ++i) {
                int L  = i * 256 + t;
                int rl = L >> 4;
                int k4 = L & 15;
                *(float4*)(&xlds[rl * 68 + k4 * 4]) = xreg[i];
            }
            __syncthreads();   // chunk kt+1 visible
        }
    }

#pragma unroll
    for (int i = 0; i < 4; ++i) {
        int rr = row0 + ty * 4 + i;
        if (rr < N_NODES) {
            float d = dis[rr];
            __half2 p0 = __floats2half2_rn(acc[i][0] * d, acc[i][1] * d);
            __half2 p1 = __floats2half2_rn(acc[i][2] * d, acc[i][3] * d);
            __half2* dst = (__half2*)(s1h + (size_t)rr * HID + tx * 4);
            dst[0] = p0;
            dst[1] = p1;
        }
    }
}

// ---------------- gather layer 1 + ELU: h1 fp32 from fp16 s1 ----------------
__global__ __launch_bounds__(256) void gather1(const __half* __restrict__ s1h,
                                               const int* __restrict__ ptr,
                                               const int* __restrict__ srcs,
                                               const float* __restrict__ dis,
                                               const float* __restrict__ b1,
                                               float* __restrict__ h1) {
    const int j = threadIdx.x & 63;
    const int v = __builtin_amdgcn_readfirstlane(blockIdx.x * 4 + (threadIdx.x >> 6));
    float acc = __half2float(s1h[(size_t)v * HID + j]);   // self-loop term
    const int beg = ptr[v];
    const int end = (v + 1 < N_NODES) ? ptr[v + 1] : N_EDGES;
    int k = beg;
    for (; k + 8 <= end; k += 8) {
        int u0 = srcs[k],     u1 = srcs[k + 1], u2 = srcs[k + 2], u3 = srcs[k + 3];
        int u4 = srcs[k + 4], u5 = srcs[k + 5], u6 = srcs[k + 6], u7 = srcs[k + 7];
        float f0 = __half2float(s1h[(size_t)u0 * HID + j]);
        float f1 = __half2float(s1h[(size_t)u1 * HID + j]);
        float f2 = __half2float(s1h[(size_t)u2 * HID + j]);
        float f3 = __half2float(s1h[(size_t)u3 * HID + j]);
        float f4 = __half2float(s1h[(size_t)u4 * HID + j]);
        float f5 = __half2float(s1h[(size_t)u5 * HID + j]);
        float f6 = __half2float(s1h[(size_t)u6 * HID + j]);
        float f7 = __half2float(s1h[(size_t)u7 * HID + j]);
        acc += ((f0 + f1) + (f2 + f3)) + ((f4 + f5) + (f6 + f7));
    }
    for (; k < end; ++k) acc += __half2float(s1h[(size_t)srcs[k] * HID + j]);
    float tt = dis[v] * acc + b1[j];
    h1[(size_t)v * HID + j] = tt > 0.f ? tt : (expf(tt) - 1.f);
}

// ---------------- GEMM2: s2h[n][j] = fp16(dis[n] * (h1[n,:] @ W2[:,j])) --------
__global__ __launch_bounds__(256) void gemm2(const float* __restrict__ h,
                                             const float* __restrict__ W2,
                                             const float* __restrict__ dis,
                                             __half* __restrict__ s2h) {
    const int j  = threadIdx.x & 31;
    const int g  = threadIdx.x >> 5;
    const int n0 = blockIdx.x * 32 + g * 4;
    const float* h0 = h + (size_t)n0 * HID;
    float a0 = 0.f, a1 = 0.f, a2 = 0.f, a3 = 0.f;
#pragma unroll 4
    for (int k = 0; k < HID; ++k) {
        float w = W2[k * OUTC + j];
        a0 += h0[k] * w;
        a1 += h0[HID + k] * w;
        a2 += h0[2 * HID + k] * w;
        a3 += h0[3 * HID + k] * w;
    }
    size_t o = (size_t)n0 * OUTC + j;
    s2h[o]            = __float2half(dis[n0]     * a0);
    s2h[o + OUTC]     = __float2half(dis[n0 + 1] * a1);
    s2h[o + 2 * OUTC] = __float2half(dis[n0 + 2] * a2);
    s2h[o + 3 * OUTC] = __float2half(dis[n0 + 3] * a3);
}

// ---------------- gather layer 2 + ELU + final projection ----------------
__global__ __launch_bounds__(256) void gather2(const __half* __restrict__ s2h,
                                               const int* __restrict__ ptr,
                                               const int* __restrict__ srcs,
                                               const float* __restrict__ dis,
                                               const float* __restrict__ b2,
                                               const float* __restrict__ Wc,
                                               const float* __restrict__ bc,
                                               float* __restrict__ out) {
    const int j = threadIdx.x & 31;
    const int v = blockIdx.x * 8 + (threadIdx.x >> 5);
    float acc = __half2float(s2h[(size_t)v * OUTC + j]);  // self-loop term
    const int beg = ptr[v];
    const int end = (v + 1 < N_NODES) ? ptr[v + 1] : N_EDGES;
    int k = beg;
    for (; k + 8 <= end; k += 8) {
        int u0 = srcs[k],     u1 = srcs[k + 1], u2 = srcs[k + 2], u3 = srcs[k + 3];
        int u4 = srcs[k + 4], u5 = srcs[k + 5], u6 = srcs[k + 6], u7 = srcs[k + 7];
        float f0 = __half2float(s2h[(size_t)u0 * OUTC + j]);
        float f1 = __half2float(s2h[(size_t)u1 * OUTC + j]);
        float f2 = __half2float(s2h[(size_t)u2 * OUTC + j]);
        float f3 = __half2float(s2h[(size_t)u3 * OUTC + j]);
        float f4 = __half2float(s2h[(size_t)u4 * OUTC + j]);
        float f5 = __half2float(s2h[(size_t)u5 * OUTC + j]);
        float f6 = __half2float(s2h[(size_t)u6 * OUTC + j]);
        float f7 = __half2float(s2h[(size_t)u7 * OUTC + j]);
        acc += ((f0 + f1) + (f2 + f3)) + ((f4 + f5) + (f6 + f7));
    }
    for (; k < end; ++k) acc += __half2float(s2h[(size_t)srcs[k] * OUTC + j]);
    float t = dis[v] * acc + b2[j];
    float hh = t > 0.f ? t : (expf(t) - 1.f);
    float p = hh * Wc[j];
#pragma unroll
    for (int off = 16; off > 0; off >>= 1) p += __shfl_xor(p, off, 64);
    if (j == 0) out[v] = p + bc[0];
}

extern "C" void kernel_launch(void* const* d_in, const int* in_sizes, int n_in,
                              void* d_out, int out_size, void* d_ws, size_t ws_size,
                              hipStream_t stream) {
    const float* x  = (const float*)d_in[0];
    const int*   ei = (const int*)d_in[1];
    const float* W1 = (const float*)d_in[2];
    const float* b1 = (const float*)d_in[3];
    const float* W2 = (const float*)d_in[4];
    const float* b2 = (const float*)d_in[5];
    const float* Wc = (const float*)d_in[6];
    const float* bc = (const float*)d_in[7];
    float* out = (float*)d_out;

    const int* row = ei;            // edge_index[0] = source
    const int* col = ei + N_EDGES;  // edge_index[1] = target

    char* ws = (char*)d_ws;
    int*    deg  = (int*)   (ws + OFF_DEG);
    int*    ptr  = (int*)   (ws + OFF_PTR);
    int*    bsum = (int*)   (ws + OFF_BSUM);
    int*    gcur = (int*)   (ws + OFF_GCUR);
    float*  dis  = (float*) (ws + OFF_DIS);
    int*    srcs = (int*)   (ws + OFF_SRC);
    int*    part = (int*)   (ws + OFF_PART);
    __half* s1h  = (__half*)(ws + OFF_S1);    // aliases part (part dead before gemm1)
    float*  h1   = (float*) (ws + OFF_H1);
    __half* s2h  = (__half*)(ws + OFF_S2);

    bucket_init    <<<(NBUCK + 255) / 256, 256, 0, stream>>>(gcur);
    partition_edges<<<(N_EDGES + CHUNK - 1) / CHUNK, 256, 0, stream>>>(row, col, gcur, part);
    bucket_hist    <<<NBUCK, 256, 0, stream>>>(gcur, part, deg, dis);
    scan_block_sums<<<NB, 256, 0, stream>>>(deg, bsum);
    scan_bsum      <<<1, 512, 0, stream>>>(bsum);
    scan_block_scan<<<NB, 256, 0, stream>>>(deg, bsum, ptr);
    bucket_fill    <<<NBUCK, 256, 0, stream>>>(gcur, part, ptr, srcs);

    gemm1  <<<(N_NODES + 63) / 64, 256, 0, stream>>>(x, W1, dis, s1h);
    gather1<<<N_NODES / 4, 256, 0, stream>>>(s1h, ptr, srcs, dis, b1, h1);
    gemm2  <<<N_NODES / 32, 256, 0, stream>>>(h1, W2, dis, s2h);
    gather2<<<N_NODES / 8, 256, 0, stream>>>(s2h, ptr, srcs, dis, b2, Wc, bc, out);
}

// Round 13
// 416.095 us; speedup vs baseline: 1.0968x; 1.0968x over previous
//
#include <hip/hip_runtime.h>
#include <hip/hip_fp16.h>
#include <math.h>

#define N_NODES 100000
#define N_EDGES 3200000
#define IN_CH   256
#define HID     64
#define OUTC    32
#define NB      ((N_NODES + 255) / 256)   // 391 scan blocks
#define NBUCK   ((N_NODES + 127) / 128)   // 782 buckets of 128 nodes (bucket = dst >> 7)
#define CHUNK   4096                      // edges per partition block
#define EPT     16                        // edges per thread (CHUNK/256)
#define CAP     4608                      // bucket capacity: mean 4092, sigma ~64 -> +8 sigma

// ---------------- workspace layout (bytes) ----------------
static constexpr size_t align256(size_t x) { return (x + 255) & ~(size_t)255; }
static constexpr size_t OFF_DEG  = 0;                                          // N ints
static constexpr size_t OFF_PTR  = OFF_DEG  + align256((size_t)N_NODES * 4);   // N ints (exclusive)
static constexpr size_t OFF_BSUM = OFF_PTR  + align256((size_t)N_NODES * 4);   // 512 ints
static constexpr size_t OFF_GCUR = OFF_BSUM + align256(512 * 4);               // NBUCK ints
static constexpr size_t OFF_DIS  = OFF_GCUR + align256((size_t)NBUCK * 4);     // N floats
static constexpr size_t OFF_SRC  = OFF_DIS  + align256((size_t)N_NODES * 4);   // E ints
static constexpr size_t OFF_PART = OFF_SRC  + align256((size_t)N_EDGES * 4);   // NBUCK*CAP ints (14.4 MB)
// s1h (N*64 halves = 12.8 MB) aliases PART (part dead after bucket_fill, before gemm1)
static constexpr size_t OFF_S1   = OFF_PART;
static constexpr size_t OFF_S2   = OFF_PART + align256((size_t)NBUCK * CAP * 4);  // N*32 halves (6.4 MB)
// total ~50 MB

// ---------------- bucket cursor init: gcur[b] = b*CAP ----------------
__global__ __launch_bounds__(256) void bucket_init(int* __restrict__ gcur) {
    int b = blockIdx.x * 256 + threadIdx.x;
    if (b < NBUCK) gcur[b] = b * CAP;
}

// ---------------- phase A: partition edges into dst-buckets (single pass) --------
__global__ __launch_bounds__(256) void partition_edges(const int* __restrict__ row,
                                                       const int* __restrict__ col,
                                                       int* __restrict__ gcur,
                                                       int* __restrict__ part) {
    __shared__ int lhist[NBUCK];
    __shared__ int lbase[NBUCK];
    const int t  = threadIdx.x;
    const int e0 = blockIdx.x * CHUNK;
    for (int i = t; i < NBUCK; i += 256) lhist[i] = 0;
    __syncthreads();

    int pk[EPT], br[EPT];
#pragma unroll
    for (int i = 0; i < EPT; ++i) {
        int e = e0 + i * 256 + t;
        if (e < N_EDGES) {
            int d = col[e];
            int b = d >> 7;
            int r = atomicAdd(&lhist[b], 1);
            pk[i] = row[e] | ((d & 127) << 17);
            br[i] = b | (r << 10);           // b<1024, r<4096 -> fits
        } else {
            br[i] = -1;
        }
    }
    __syncthreads();

    const int off = (int)((blockIdx.x * 131u) % NBUCK);
    for (int i = t; i < NBUCK; i += 256) {
        int bb = i + off;
        if (bb >= NBUCK) bb -= NBUCK;
        int c = lhist[bb];
        lbase[bb] = (c > 0) ? atomicAdd(&gcur[bb], c) : 0;
    }
    __syncthreads();

#pragma unroll
    for (int i = 0; i < EPT; ++i) {
        if (br[i] >= 0) {
            int b = br[i] & 1023;
            int r = br[i] >> 10;
            part[lbase[b] + r] = pk[i];
        }
    }
}

// ---------------- phase B1: per-node degree + dis from bucket data ---------------
__global__ __launch_bounds__(256) void bucket_hist(const int* __restrict__ gcur,
                                                   const int* __restrict__ part,
                                                   int* __restrict__ deg,
                                                   float* __restrict__ dis) {
    __shared__ int lh[128];
    const int b = blockIdx.x;
    const int t = threadIdx.x;
    if (t < 128) lh[t] = 0;
    __syncthreads();
    const int cnt = gcur[b] - b * CAP;
    for (int i = t; i < cnt; i += 256)
        atomicAdd(&lh[part[(size_t)b * CAP + i] >> 17], 1);
    __syncthreads();
    int v = b * 128 + t;
    if (t < 128 && v < N_NODES) {
        int d = lh[t];
        deg[v] = d;
        dis[v] = rsqrtf((float)d + 1.0f);   // +1 self-loop
    }
}

// ---------------- 3-kernel exclusive scan of deg -> ptr ----------------
__global__ __launch_bounds__(256) void scan_block_sums(const int* __restrict__ deg,
                                                       int* __restrict__ bsum) {
    __shared__ int buf[256];
    unsigned i = blockIdx.x * 256u + threadIdx.x;
    int v = (i < N_NODES) ? deg[i] : 0;
    buf[threadIdx.x] = v;
    __syncthreads();
    for (int off = 128; off > 0; off >>= 1) {
        if (threadIdx.x < (unsigned)off) buf[threadIdx.x] += buf[threadIdx.x + off];
        __syncthreads();
    }
    if (threadIdx.x == 0) bsum[blockIdx.x] = buf[0];
}

__global__ __launch_bounds__(512) void scan_bsum(int* __restrict__ bsum) {
    __shared__ int buf[512];
    int t = threadIdx.x;
    int v = (t < NB) ? bsum[t] : 0;
    buf[t] = v;
    __syncthreads();
    for (int off = 1; off < 512; off <<= 1) {
        int add = (t >= off) ? buf[t - off] : 0;
        __syncthreads();
        buf[t] += add;
        __syncthreads();
    }
    if (t < NB) bsum[t] = buf[t] - v;  // exclusive
}

__global__ __launch_bounds__(256) void scan_block_scan(const int* __restrict__ deg,
                                                       const int* __restrict__ bsum,
                                                       int* __restrict__ ptr) {
    __shared__ int buf[256];
    unsigned i = blockIdx.x * 256u + threadIdx.x;
    int v = (i < N_NODES) ? deg[i] : 0;
    buf[threadIdx.x] = v;
    __syncthreads();
    for (int off = 1; off < 256; off <<= 1) {
        int add = (threadIdx.x >= (unsigned)off) ? buf[threadIdx.x - off] : 0;
        __syncthreads();
        buf[threadIdx.x] += add;
        __syncthreads();
    }
    if (i < N_NODES) ptr[i] = bsum[blockIdx.x] + buf[threadIdx.x] - v;  // exclusive
}

// ---------------- phase B2: fill srcs; writes confined to ~16KB window/block -------
__global__ __launch_bounds__(256) void bucket_fill(const int* __restrict__ gcur,
                                                   const int* __restrict__ part,
                                                   const int* __restrict__ ptr,
                                                   int* __restrict__ srcs) {
    __shared__ int lcur[128];
    const int b = blockIdx.x;
    const int t = threadIdx.x;
    if (t < 128) lcur[t] = 0;
    __syncthreads();
    const int cnt = gcur[b] - b * CAP;
    for (int i = t; i < cnt; i += 256) {
        int p    = part[(size_t)b * CAP + i];
        int dlow = p >> 17;
        int src  = p & 0x1FFFF;
        int r    = atomicAdd(&lcur[dlow], 1);        // LDS cursor
        srcs[ptr[b * 128 + dlow] + r] = src;
    }
}

// ---------------- GEMM1: s1h[n][j] = fp16(dis[n] * (x[n,:] @ W1[:,j])) ----------
// r11 version EXACTLY (71 us): serial stage->barrier->compute->barrier. The r12
// register-prefetch pipeline spilled (WRITE_SIZE 12.5->90 MB) and regressed.
__global__ __launch_bounds__(256) void gemm1(const float* __restrict__ x,
                                             const float* __restrict__ W1,
                                             const float* __restrict__ dis,
                                             __half* __restrict__ s1h) {
    __shared__ float wlds[64 * HID];   // 16 KB k-chunk of W1: [k_local][j]
    __shared__ float xlds[64 * 68];    // 17 KB x-tile: [row_local][k_local], stride 68

    const int t  = threadIdx.x;
    const int tx = t & 15;
    const int ty = t >> 4;
    const int row0 = blockIdx.x * 64;

    float acc[4][4] = {{0.f}};

    for (int kt = 0; kt < IN_CH / 64; ++kt) {
        {
            const float4* w4 = (const float4*)(W1 + (size_t)kt * 64 * HID);
            float4* l4 = (float4*)wlds;
#pragma unroll
            for (int i = 0; i < 4; ++i) l4[i * 256 + t] = w4[i * 256 + t];
        }
        {
#pragma unroll
            for (int i = 0; i < 4; ++i) {
                int L  = i * 256 + t;
                int rl = L >> 4;
                int k4 = L & 15;
                int rg = row0 + rl;
                float4 v;
                if (rg < N_NODES) v = ((const float4*)x)[(size_t)rg * 64 + kt * 16 + k4];
                else              v = make_float4(0.f, 0.f, 0.f, 0.f);
                *(float4*)(&xlds[rl * 68 + k4 * 4]) = v;
            }
        }
        __syncthreads();

        const float4* wl4 = (const float4*)wlds;
#pragma unroll 4
        for (int k4 = 0; k4 < 16; ++k4) {
            float4 xv[4];
#pragma unroll
            for (int i = 0; i < 4; ++i)
                xv[i] = *(const float4*)(&xlds[(ty * 4 + i) * 68 + k4 * 4]);
#pragma unroll
            for (int kk = 0; kk < 4; ++kk) {
                float4 bv = wl4[(k4 * 4 + kk) * 16 + tx];
#pragma unroll
                for (int i = 0; i < 4; ++i) {
                    const float* xf = (const float*)&xv[i];
                    float a = xf[kk];
                    acc[i][0] += a * bv.x;
                    acc[i][1] += a * bv.y;
                    acc[i][2] += a * bv.z;
                    acc[i][3] += a * bv.w;
                }
            }
        }
        __syncthreads();
    }

#pragma unroll
    for (int i = 0; i < 4; ++i) {
        int rr = row0 + ty * 4 + i;
        if (rr < N_NODES) {
            float d = dis[rr];
            __half2 p0 = __floats2half2_rn(acc[i][0] * d, acc[i][1] * d);
            __half2 p1 = __floats2half2_rn(acc[i][2] * d, acc[i][3] * d);
            __half2* dst = (__half2*)(s1h + (size_t)rr * HID + tx * 4);
            dst[0] = p0;
            dst[1] = p1;
        }
    }
}

// ---------------- gather1 + ELU + FUSED GEMM2: s2h = fp16(dis*(ELU(...)@W2)) ----
// One wave per node. After aggregation+ELU the wave holds h1[v][j] in lane j;
// instead of round-tripping h1 through HBM (25.6 MB write + 25.6 MB read in a
// separate gemm2), compute the 64x32 matvec in-wave: h -> per-wave LDS row
// (in-wave RAW, no barrier), halves of k split across lane groups (32 FMA/lane,
// broadcast h reads; W2 stride-1 = 2-way bank alias, free), one shfl_xor(32)
// combine. gather1 is memory-bound (12% VALU) so the extra ALU is free.
__global__ __launch_bounds__(256) void gather1(const __half* __restrict__ s1h,
                                               const int* __restrict__ ptr,
                                               const int* __restrict__ srcs,
                                               const float* __restrict__ dis,
                                               const float* __restrict__ b1,
                                               const float* __restrict__ W2,
                                               __half* __restrict__ s2h) {
    __shared__ float w2lds[HID * OUTC];   // 8 KB: [k][jo]
    __shared__ float hbuf[4][HID];        // per-wave ELU'd h row

    const int t = threadIdx.x;
    // stage W2 once per block
    {
        float4* l4 = (float4*)w2lds;
        const float4* s4 = (const float4*)W2;
        l4[t] = s4[t];
        l4[256 + t] = s4[256 + t];
    }
    __syncthreads();

    const int j = t & 63;
    const int w = t >> 6;
    const int v = __builtin_amdgcn_readfirstlane(blockIdx.x * 4 + w);
    float acc = __half2float(s1h[(size_t)v * HID + j]);   // self-loop term
    const int beg = ptr[v];
    const int end = (v + 1 < N_NODES) ? ptr[v + 1] : N_EDGES;
    int k = beg;
    for (; k + 8 <= end; k += 8) {
        int u0 = srcs[k],     u1 = srcs[k + 1], u2 = srcs[k + 2], u3 = srcs[k + 3];
        int u4 = srcs[k + 4], u5 = srcs[k + 5], u6 = srcs[k + 6], u7 = srcs[k + 7];
        float f0 = __half2float(s1h[(size_t)u0 * HID + j]);
        float f1 = __half2float(s1h[(size_t)u1 * HID + j]);
        float f2 = __half2float(s1h[(size_t)u2 * HID + j]);
        float f3 = __half2float(s1h[(size_t)u3 * HID + j]);
        float f4 = __half2float(s1h[(size_t)u4 * HID + j]);
        float f5 = __half2float(s1h[(size_t)u5 * HID + j]);
        float f6 = __half2float(s1h[(size_t)u6 * HID + j]);
        float f7 = __half2float(s1h[(size_t)u7 * HID + j]);
        acc += ((f0 + f1) + (f2 + f3)) + ((f4 + f5) + (f6 + f7));
    }
    for (; k < end; ++k) acc += __half2float(s1h[(size_t)srcs[k] * HID + j]);
    float tt = dis[v] * acc + b1[j];
    float hh = tt > 0.f ? tt : (expf(tt) - 1.f);

    // ---- fused gemm2: s2[v][jo] = dis[v] * sum_k hh[k] * W2[k][jo]
    hbuf[w][j] = hh;                       // in-wave RAW; compiler inserts lgkmcnt wait
    const int jo = j & 31;
    const int kb = (j >> 5) * 32;          // lower lanes: k 0..31, upper: 32..63
    float p = 0.f;
#pragma unroll
    for (int kk = 0; kk < 32; ++kk)
        p += hbuf[w][kb + kk] * w2lds[(kb + kk) * OUTC + jo];
    p += __shfl_xor(p, 32, 64);            // combine the two k-halves
    if (j < 32) {
        s2h[(size_t)v * OUTC + jo] = __float2half(dis[v] * p);
    }
}

// ---------------- gather layer 2 + ELU + final projection ----------------
__global__ __launch_bounds__(256) void gather2(const __half* __restrict__ s2h,
                                               const int* __restrict__ ptr,
                                               const int* __restrict__ srcs,
                                               const float* __restrict__ dis,
                                               const float* __restrict__ b2,
                                               const float* __restrict__ Wc,
                                               const float* __restrict__ bc,
                                               float* __restrict__ out) {
    const int j = threadIdx.x & 31;
    const int v = blockIdx.x * 8 + (threadIdx.x >> 5);
    float acc = __half2float(s2h[(size_t)v * OUTC + j]);  // self-loop term
    const int beg = ptr[v];
    const int end = (v + 1 < N_NODES) ? ptr[v + 1] : N_EDGES;
    int k = beg;
    for (; k + 8 <= end; k += 8) {
        int u0 = srcs[k],     u1 = srcs[k + 1], u2 = srcs[k + 2], u3 = srcs[k + 3];
        int u4 = srcs[k + 4], u5 = srcs[k + 5], u6 = srcs[k + 6], u7 = srcs[k + 7];
        float f0 = __half2float(s2h[(size_t)u0 * OUTC + j]);
        float f1 = __half2float(s2h[(size_t)u1 * OUTC + j]);
        float f2 = __half2float(s2h[(size_t)u2 * OUTC + j]);
        float f3 = __half2float(s2h[(size_t)u3 * OUTC + j]);
        float f4 = __half2float(s2h[(size_t)u4 * OUTC + j]);
        float f5 = __half2float(s2h[(size_t)u5 * OUTC + j]);
        float f6 = __half2float(s2h[(size_t)u6 * OUTC + j]);
        float f7 = __half2float(s2h[(size_t)u7 * OUTC + j]);
        acc += ((f0 + f1) + (f2 + f3)) + ((f4 + f5) + (f6 + f7));
    }
    for (; k < end; ++k) acc += __half2float(s2h[(size_t)srcs[k] * OUTC + j]);
    float t = dis[v] * acc + b2[j];
    float hh = t > 0.f ? t : (expf(t) - 1.f);
    float p = hh * Wc[j];
#pragma unroll
    for (int off = 16; off > 0; off >>= 1) p += __shfl_xor(p, off, 64);
    if (j == 0) out[v] = p + bc[0];
}

extern "C" void kernel_launch(void* const* d_in, const int* in_sizes, int n_in,
                              void* d_out, int out_size, void* d_ws, size_t ws_size,
                              hipStream_t stream) {
    const float* x  = (const float*)d_in[0];
    const int*   ei = (const int*)d_in[1];
    const float* W1 = (const float*)d_in[2];
    const float* b1 = (const float*)d_in[3];
    const float* W2 = (const float*)d_in[4];
    const float* b2 = (const float*)d_in[5];
    const float* Wc = (const float*)d_in[6];
    const float* bc = (const float*)d_in[7];
    float* out = (float*)d_out;

    const int* row = ei;            // edge_index[0] = source
    const int* col = ei + N_EDGES;  // edge_index[1] = target

    char* ws = (char*)d_ws;
    int*    deg  = (int*)   (ws + OFF_DEG);
    int*    ptr  = (int*)   (ws + OFF_PTR);
    int*    bsum = (int*)   (ws + OFF_BSUM);
    int*    gcur = (int*)   (ws + OFF_GCUR);
    float*  dis  = (float*) (ws + OFF_DIS);
    int*    srcs = (int*)   (ws + OFF_SRC);
    int*    part = (int*)   (ws + OFF_PART);
    __half* s1h  = (__half*)(ws + OFF_S1);    // aliases part (part dead before gemm1)
    __half* s2h  = (__half*)(ws + OFF_S2);

    bucket_init    <<<(NBUCK + 255) / 256, 256, 0, stream>>>(gcur);
    partition_edges<<<(N_EDGES + CHUNK - 1) / CHUNK, 256, 0, stream>>>(row, col, gcur, part);
    bucket_hist    <<<NBUCK, 256, 0, stream>>>(gcur, part, deg, dis);
    scan_block_sums<<<NB, 256, 0, stream>>>(deg, bsum);
    scan_bsum      <<<1, 512, 0, stream>>>(bsum);
    scan_block_scan<<<NB, 256, 0, stream>>>(deg, bsum, ptr);
    bucket_fill    <<<NBUCK, 256, 0, stream>>>(gcur, part, ptr, srcs);

    gemm1  <<<(N_NODES + 63) / 64, 256, 0, stream>>>(x, W1, dis, s1h);
    gather1<<<N_NODES / 4, 256, 0, stream>>>(s1h, ptr, srcs, dis, b1, W2, s2h);
    gather2<<<N_NODES / 8, 256, 0, stream>>>(s2h, ptr, srcs, dis, b2, Wc, bc, out);
}